// Round 6
// baseline (387.003 us; speedup 1.0000x reference)
//
#include <hip/hip_runtime.h>
#include <math.h>

using uint = unsigned int;
typedef _Float16 h2    __attribute__((ext_vector_type(2)));
typedef _Float16 f16x8 __attribute__((ext_vector_type(8)));
typedef float    f32x4 __attribute__((ext_vector_type(4)));

#define N_ATOMS 8192
#define NEDGE   262144
#define KNBR    32
#define NGAUSS  50
#define NLAYER  6
#define NB      32
#define GTAB    1024
#define DMAX    8.6603f
#define FCUT    10.0f
#define MB      1048576

// LDS geometry (uints). MFMA stride 76: 16B-aligned frags, 2-way banks (free).
#define LSTRIDE 76
#define S_WT    0               // 128*76 = 9728
#define S_AS    9728            // 16*76 = 1216
#define S_TS    10944           // 1216
// table-build regions (reused after layer phases, sequential w/ syncthreads)
#define T_W1    0               // 4096 (kp<32, c<128)
#define T_W2    4096            // 8192
#define T_RBF   12288           // 1024
#define T_HID   13312           // 2048
#define SMEM_N  15616           // 62464 B -> 2 blocks/CU

// wpack layout (uints)
#define OW1P_OFF 147456         // 18 mats 128x128 (c,kp) order: cf1 x6 | cf2 x6 | int x6
#define M1_OFF   151552         // + ow1^T 64x64 (c,kp)
#define M2_OFF   176128         // + mlp_w1 f16 (kp,c) x6
#define WPACK_N  225280         // + mlp_w2 f16 (kp,c) x6

__device__ __forceinline__ float ssp(float x) {
    return fmaxf(x, 0.0f) + log1pf(expf(-fabsf(x))) - 0.69314718055994531f;
}
__device__ __forceinline__ uint pack2(float a, float b) {
    union { h2 h; uint u; } x;
    h2 v; v.x = (_Float16)a; v.y = (_Float16)b; x.h = v; return x.u;
}
__device__ __forceinline__ float2 h2f2(uint u) {
    union { uint u; h2 h; } x; x.u = u;
    float2 r; r.x = (float)x.h.x; r.y = (float)x.h.y; return r;
}
__device__ __forceinline__ float fdot2f(h2 a, h2 b, float c) {
#if __has_builtin(__builtin_amdgcn_fdot2)
    return __builtin_amdgcn_fdot2(a, b, c, false);
#else
    return fmaf((float)a.y, (float)b.y, fmaf((float)a.x, (float)b.x, c));
#endif
}
__device__ __forceinline__ h2 u2h(uint u) {
    union { uint u; h2 h; } x; x.u = u; return x.h;
}

// copy pre-packed W^T (c,kp) 64-stride -> LDS stride-76
__device__ __forceinline__ void stage_cp(uint* sm, const uint* __restrict__ src,
                                         int n16, int tid) {
    for (int i = tid; i < n16; i += 256) {
        uint4 v = ((const uint4*)src)[i];
        *(uint4*)&sm[(i >> 4) * LSTRIDE + (i & 15) * 4] = v;
    }
}

// MFMA: D[16 rows][NCT*16 cols] = As(16x128) @ WT^T, cols base nb
template<int NCT>
__device__ __forceinline__ void run_gemm(const uint* sm, int as_off, int lane,
                                         int nb, f32x4* acc) {
    int m = lane & 15, q = lane >> 4;
    #pragma unroll
    for (int ks = 0; ks < 4; ++ks) {
        f16x8 a = *(const f16x8*)&sm[as_off + m * LSTRIDE + q * 4 + ks * 16];
        #pragma unroll
        for (int ct = 0; ct < NCT; ++ct) {
            f16x8 b = *(const f16x8*)&sm[S_WT + (nb + ct * 16 + m) * LSTRIDE + q * 4 + ks * 16];
            acc[ct] = __builtin_amdgcn_mfma_f32_16x16x32_f16(a, b, acc[ct], 0, 0, 0);
        }
    }
}

// table chunk (32 entries at `base`) for one layer: assumes T_W1/T_W2 staged.
__device__ void table_gemm(uint* sm, const float* __restrict__ b1l,
                           const float* __restrict__ b2l,
                           uint* __restrict__ tab_l, int base, int tid) {
    const float delta = DMAX / (float)(GTAB - 1);
    const float gstep = FCUT / (float)(NGAUSS - 1);
    const float coeff = -0.5f / (gstep * gstep);
    for (int i = tid; i < 1024; i += 256) {
        int r = i >> 5, kp = i & 31;
        float dv = (float)(base + r) * delta;
        int g0 = 2 * kp;
        float v0 = 0.f, v1 = 0.f;
        if (g0 < NGAUSS)     { float t = dv - (float)g0 * gstep;     v0 = expf(coeff*t*t); }
        if (g0 + 1 < NGAUSS) { float t = dv - (float)(g0+1) * gstep; v1 = expf(coeff*t*t); }
        sm[T_RBF + i] = pack2(v0, v1);
    }
    __syncthreads();
    int tx = tid & 31, ty = tid >> 5, c0 = tx * 4, tr0 = ty * 4;
    float acc[4][4];
    #pragma unroll
    for (int i = 0; i < 4; ++i) { acc[i][0]=0.f; acc[i][1]=0.f; acc[i][2]=0.f; acc[i][3]=0.f; }
    #pragma unroll
    for (int oct = 0; oct < 8; ++oct) {              // stage 1: K=50 (32 pairs)
        int kp0 = oct * 4;
        uint4 w_[4];
        #pragma unroll
        for (int p = 0; p < 4; ++p) w_[p] = *(const uint4*)&sm[T_W1 + (kp0+p)*128 + c0];
        #pragma unroll
        for (int i = 0; i < 4; ++i) {
            uint4 av = *(const uint4*)&sm[T_RBF + (tr0+i)*32 + kp0];
            uint aa[4] = {av.x, av.y, av.z, av.w};
            #pragma unroll
            for (int p = 0; p < 4; ++p) {
                h2 ap = u2h(aa[p]);
                acc[i][0] = fdot2f(ap, u2h(w_[p].x), acc[i][0]);
                acc[i][1] = fdot2f(ap, u2h(w_[p].y), acc[i][1]);
                acc[i][2] = fdot2f(ap, u2h(w_[p].z), acc[i][2]);
                acc[i][3] = fdot2f(ap, u2h(w_[p].w), acc[i][3]);
            }
        }
    }
    float4 b1v = *(const float4*)&b1l[c0];
    #pragma unroll
    for (int i = 0; i < 4; ++i) {
        uint2 o;
        o.x = pack2(ssp(acc[i][0] + b1v.x), ssp(acc[i][1] + b1v.y));
        o.y = pack2(ssp(acc[i][2] + b1v.z), ssp(acc[i][3] + b1v.w));
        *(uint2*)&sm[T_HID + (tr0+i)*64 + (c0 >> 1)] = o;
    }
    __syncthreads();
    float acc2[4][4];
    #pragma unroll
    for (int i = 0; i < 4; ++i) { acc2[i][0]=0.f; acc2[i][1]=0.f; acc2[i][2]=0.f; acc2[i][3]=0.f; }
    #pragma unroll 4
    for (int oct = 0; oct < 16; ++oct) {             // stage 2: K=128
        int kp0 = oct * 4;
        uint4 w_[4];
        #pragma unroll
        for (int p = 0; p < 4; ++p) w_[p] = *(const uint4*)&sm[T_W2 + (kp0+p)*128 + c0];
        #pragma unroll
        for (int i = 0; i < 4; ++i) {
            uint4 av = *(const uint4*)&sm[T_HID + (tr0+i)*64 + kp0];
            uint aa[4] = {av.x, av.y, av.z, av.w};
            #pragma unroll
            for (int p = 0; p < 4; ++p) {
                h2 ap = u2h(aa[p]);
                acc2[i][0] = fdot2f(ap, u2h(w_[p].x), acc2[i][0]);
                acc2[i][1] = fdot2f(ap, u2h(w_[p].y), acc2[i][1]);
                acc2[i][2] = fdot2f(ap, u2h(w_[p].z), acc2[i][2]);
                acc2[i][3] = fdot2f(ap, u2h(w_[p].w), acc2[i][3]);
            }
        }
    }
    const float delta2 = DMAX / (float)(GTAB - 1);
    float4 b2v = *(const float4*)&b2l[c0];
    #pragma unroll
    for (int i = 0; i < 4; ++i) {
        int row = base + tr0 + i;
        float dv = (float)row * delta2;
        float Cd = 0.5f * (cosf(dv * 0.3141592653589793f) + 1.0f);
        uint2 o;
        o.x = pack2((acc2[i][0] + b2v.x)*Cd, (acc2[i][1] + b2v.y)*Cd);
        o.y = pack2((acc2[i][2] + b2v.z)*Cd, (acc2[i][3] + b2v.w)*Cd);
        *(uint2*)&tab_l[row*64 + (c0 >> 1)] = o;
    }
}

struct SArgs {
    const float *pos; const int *z; const int *ei; const int *dom;
    const float *emb;
    const float *cf1; const float *cf2w; const float *intw; const float *ow1;
    const float *mw1; const float *mb1; const float *mw2; const float *mb2;
    const float *dome; const float *fw1; const float *fb1;
    const float *fw2; const float *fb2; const float *bw; const float *bb;
    uint2 *epack; uint *tab; float *h; uint *xA;
    float *gbias; uint *wpack; float *out; int out_size;
};

// ---------------------------------------------------------------------------
// setup: zero-out + wcvt + epack + embed + x0 GEMM + film(blocks 32..63)
//        + tab_0 build (blocks 0..31, fp32 weight staging)
__global__ void __launch_bounds__(256) k_setup(SArgs a) {
    __shared__ __align__(16) uint sm[SMEM_N];
    const int tid = threadIdx.x, bid = blockIdx.x;
    const int gidx = bid * 256 + tid, gsz = 512 * 256;
    const int lane = tid & 63, w = tid >> 6;
    const int m = lane & 15, q = lane >> 4;
    const int rowbase = bid * 16;

    for (int i = gidx; i < a.out_size; i += gsz) a.out[i] = 0.0f;

    // f16 weight pack: cf/int (c,kp) for MFMA; ow1^T; mlp_w1/w2 (kp,c) for tables
    for (int idx = gidx; idx < WPACK_N; idx += gsz) {
        if (idx < OW1P_OFF) {
            int mat = idx >> 13, e = idx & 8191;
            int kp = e >> 7, c = e & 127;
            const float* src = (mat < 6) ? (a.cf1 + mat * 16384)
                            : (mat < 12) ? (a.cf2w + (mat - 6) * 16384)
                                         : (a.intw + (mat - 12) * 16384);
            a.wpack[mat * 8192 + c * 64 + kp] =
                pack2(src[2 * kp * 128 + c], src[(2 * kp + 1) * 128 + c]);
        } else if (idx < M1_OFF) {
            int e = idx - OW1P_OFF;
            int kp = e >> 6, c = e & 63;
            a.wpack[OW1P_OFF + c * 64 + kp] =
                pack2(a.ow1[2 * kp * 64 + c], a.ow1[(2 * kp + 1) * 64 + c]);
        } else if (idx < M2_OFF) {
            int e = idx - M1_OFF;
            int l = e >> 12, r = e & 4095;
            int kp = r >> 7, c = r & 127;
            int g0 = 2 * kp;
            float va = (g0 < NGAUSS)     ? a.mw1[l*NGAUSS*128 + g0*128 + c]     : 0.f;
            float vb = (g0 + 1 < NGAUSS) ? a.mw1[l*NGAUSS*128 + (g0+1)*128 + c] : 0.f;
            a.wpack[idx] = pack2(va, vb);
        } else {
            int e = idx - M2_OFF;
            int l = e >> 13, r = e & 8191;
            int kp = r >> 7, c = r & 127;
            a.wpack[idx] = pack2(a.mw2[l*16384 + 2*kp*128 + c],
                                 a.mw2[l*16384 + (2*kp+1)*128 + c]);
        }
    }

    // epack: local 512 edges
    const float invdelta = (float)(GTAB - 1) / DMAX;
    #pragma unroll
    for (int t = 0; t < 2; ++t) {
        int e = rowbase * KNBR + t * 256 + tid;
        int s = a.ei[e], d = a.ei[NEDGE + e];
        float dx = a.pos[3*s] - a.pos[3*d];
        float dy = a.pos[3*s+1] - a.pos[3*d+1];
        float dz = a.pos[3*s+2] - a.pos[3*d+2];
        float dist = sqrtf(dx*dx + dy*dy + dz*dz);
        float u = dist * invdelta;
        int i0 = (int)u; i0 = (i0 < GTAB - 2) ? i0 : (GTAB - 2);
        float t2 = u - (float)i0;
        uint tb = pack2(t2, 0.0f) & 0xffffu;
        uint2 ep; ep.x = (uint)s; ep.y = (tb << 16) | (uint)i0;
        a.epack[e] = ep;
    }

    // embed -> h (f32) + As (f16)
    for (int i = tid; i < 1024; i += 256) {
        int r = i >> 6, f2 = i & 63;
        int zz = a.z[rowbase + r];
        float2 v = *(const float2*)&a.emb[zz * 128 + f2 * 2];
        *(float2*)&a.h[(rowbase + r) * 128 + f2 * 2] = v;
        sm[S_AS + r * LSTRIDE + f2] = pack2(v.x, v.y);
    }
    // WT <- cf1_0 (fp32 direct; wpack not yet visible within this kernel)
    for (int i = tid; i < 2048; i += 256) {
        int m4 = i >> 7, c = i & 127;
        float v[8];
        #pragma unroll
        for (int j = 0; j < 8; ++j) v[j] = a.cf1[(8 * m4 + j) * 128 + c];
        uint4 pk; pk.x = pack2(v[0], v[1]); pk.y = pack2(v[2], v[3]);
        pk.z = pack2(v[4], v[5]); pk.w = pack2(v[6], v[7]);
        *(uint4*)&sm[c * LSTRIDE + m4 * 4] = pk;
    }
    __syncthreads();
    {   // x0 = h @ W1_0 -> xA
        f32x4 acc[2] = {{0,0,0,0},{0,0,0,0}};
        run_gemm<2>(sm, S_AS, lane, w * 32, acc);
        #pragma unroll
        for (int ct = 0; ct < 2; ++ct) {
            int n = w * 32 + ct * 16 + m;
            #pragma unroll
            for (int i = 0; i < 4; ++i) {
                float v = acc[ct][i];
                float u = __shfl_xor(v, 1, 64);
                if (!(lane & 1))
                    a.xA[(rowbase + q * 4 + i) * 64 + (n >> 1)] = pack2(v, u);
            }
        }
    }
    __syncthreads();
    if (bid >= 32 && bid < 64) {
        // FiLM beta sum (gamma path multiplies zeros), graph = bid-32
        int g = bid - 32;
        float* fs = (float*)sm;   // des@0, a1@64, film@192, part@320
        if (tid < 64) fs[tid] = a.dome[a.dom[g] * 64 + tid];
        __syncthreads();
        if (tid < 128) {
            float acc = a.fb1[tid];
            for (int i = 0; i < 64; ++i) acc = fmaf(fs[i], a.fw1[i*128 + tid], acc);
            fs[64 + tid] = fmaxf(acc, 0.0f);
        }
        __syncthreads();
        if (tid < 128) {
            float acc = a.fb2[tid];
            for (int i = 0; i < 128; ++i) acc = fmaf(fs[64+i], a.fw2[i*128 + tid], acc);
            fs[192 + tid] = acc;
        }
        __syncthreads();
        if (tid < 128) {
            float acc = a.bb[tid];
            for (int i = 0; i < 128; ++i) acc = fmaf(fs[192+i], a.bw[i*128 + tid], acc);
            #pragma unroll
            for (int off = 32; off > 0; off >>= 1) acc += __shfl_down(acc, off, 64);
            if ((tid & 63) == 0) fs[320 + (tid >> 6)] = acc;
        }
        __syncthreads();
        if (tid == 0) a.gbias[g] = fs[320] + fs[321];
    } else if (bid < 32) {
        // tab_0 chunk: stage fp32 mlp weights of layer 0, then GEMM
        for (int i = tid; i < 4096; i += 256) {
            int kp = i >> 7, c = i & 127;
            int g0 = 2 * kp;
            float va = (g0 < NGAUSS)     ? a.mw1[g0*128 + c]     : 0.f;
            float vb = (g0 + 1 < NGAUSS) ? a.mw1[(g0+1)*128 + c] : 0.f;
            sm[T_W1 + i] = pack2(va, vb);
        }
        for (int i = tid; i < 8192; i += 256) {
            int kp = i >> 7, c = i & 127;
            sm[T_W2 + i] = pack2(a.mw2[2*kp*128 + c], a.mw2[(2*kp+1)*128 + c]);
        }
        table_gemm(sm, a.mb1, a.mb2, a.tab, bid * 32, tid);
    }
}

// ---------------------------------------------------------------------------
// fused layer: gather -> ssp(.@W2+b2) -> h += .@W3+b3 -> x_next = h@W1n (MFMA)
// blocks 0..31 additionally build tab_{l+1} (hidden behind other blocks' work)
template<bool LAST>
__global__ void __launch_bounds__(256) k_layer(
    float* __restrict__ h, const uint* __restrict__ xin, uint* __restrict__ xout,
    const uint* __restrict__ tabl, const uint2* __restrict__ epack,
    const uint* __restrict__ w2p, const uint* __restrict__ w3p,
    const uint* __restrict__ w1np,
    const float* __restrict__ b2, const float* __restrict__ b3,
    const uint* __restrict__ wpack, int lnext,
    const float* __restrict__ mb1, const float* __restrict__ mb2,
    uint* __restrict__ tabn,
    const float* __restrict__ ob1, const float* __restrict__ ow2,
    const float* __restrict__ ob2, const float* __restrict__ gbias,
    float* __restrict__ out) {
    __shared__ __align__(16) uint sm[SMEM_N];
    const int tid = threadIdx.x, bid = blockIdx.x;
    const int lane = tid & 63, w = tid >> 6;
    const int m = lane & 15, q = lane >> 4;
    const int rowbase = bid * 16;

    stage_cp(sm, w2p, 2048, tid);
    {   // gather 16 atoms x 32 edges
        int f2 = lane;
        #pragma unroll
        for (int p = 0; p < 4; ++p) {
            int al = p * 4 + w;
            int ebase = (rowbase + al) * KNBR;
            float ax = 0.f, ay = 0.f;
            #pragma unroll 4
            for (int k = 0; k < KNBR; ++k) {
                uint2 ep = epack[ebase + k];
                int s  = (int)ep.x;
                int i0 = (int)(ep.y & 0xffffu);
                float t = h2f2(ep.y).y;
                float2 f0 = h2f2(tabl[i0 * 64 + f2]);
                float2 f1 = h2f2(tabl[(i0 + 1) * 64 + f2]);
                float2 xs = h2f2(xin[s * 64 + f2]);
                ax = fmaf(xs.x, fmaf(t, f1.x - f0.x, f0.x), ax);
                ay = fmaf(xs.y, fmaf(t, f1.y - f0.y, f0.y), ay);
            }
            sm[S_AS + al * LSTRIDE + f2] = pack2(ax, ay);
        }
    }
    __syncthreads();
    {   // Ts = ssp(As @ W2 + b2)
        f32x4 acc[2] = {{0,0,0,0},{0,0,0,0}};
        run_gemm<2>(sm, S_AS, lane, w * 32, acc);
        #pragma unroll
        for (int ct = 0; ct < 2; ++ct) {
            int n = w * 32 + ct * 16 + m;
            float bv = b2[n];
            #pragma unroll
            for (int i = 0; i < 4; ++i) {
                float v = ssp(acc[ct][i] + bv);
                float u = __shfl_xor(v, 1, 64);
                if (!(lane & 1))
                    sm[S_TS + (q * 4 + i) * LSTRIDE + (n >> 1)] = pack2(v, u);
            }
        }
    }
    __syncthreads();
    stage_cp(sm, w3p, 2048, tid);
    __syncthreads();
    {   // h += Ts @ W3 + b3 ; As <- h_new
        f32x4 acc[2] = {{0,0,0,0},{0,0,0,0}};
        run_gemm<2>(sm, S_TS, lane, w * 32, acc);
        #pragma unroll
        for (int ct = 0; ct < 2; ++ct) {
            int n = w * 32 + ct * 16 + m;
            float bv = b3[n];
            #pragma unroll
            for (int i = 0; i < 4; ++i) {
                int r = rowbase + q * 4 + i;
                float hv = h[r * 128 + n] + acc[ct][i] + bv;
                h[r * 128 + n] = hv;
                float u = __shfl_xor(hv, 1, 64);
                if (!(lane & 1))
                    sm[S_AS + (q * 4 + i) * LSTRIDE + (n >> 1)] = pack2(hv, u);
            }
        }
    }
    __syncthreads();
    if (!LAST) {
        stage_cp(sm, w1np, 2048, tid);
        __syncthreads();
        f32x4 acc[2] = {{0,0,0,0},{0,0,0,0}};
        run_gemm<2>(sm, S_AS, lane, w * 32, acc);
        #pragma unroll
        for (int ct = 0; ct < 2; ++ct) {
            int n = w * 32 + ct * 16 + m;
            #pragma unroll
            for (int i = 0; i < 4; ++i) {
                float v = acc[ct][i];
                float u = __shfl_xor(v, 1, 64);
                if (!(lane & 1))
                    xout[(rowbase + q * 4 + i) * 64 + (n >> 1)] = pack2(v, u);
            }
        }
        // hidden table build for layer lnext (32 chunks of 32 entries)
        if (bid < 32) {
            __syncthreads();
            { const uint4* s4 = (const uint4*)(wpack + M1_OFF + lnext*4096);
              uint4* d4 = (uint4*)&sm[T_W1];
              for (int i = tid; i < 1024; i += 256) d4[i] = s4[i]; }
            { const uint4* s4 = (const uint4*)(wpack + M2_OFF + lnext*8192);
              uint4* d4 = (uint4*)&sm[T_W2];
              for (int i = tid; i < 2048; i += 256) d4[i] = s4[i]; }
            table_gemm(sm, mb1 + lnext*128, mb2 + lnext*128, tabn, bid * 32, tid);
        }
    } else {
        stage_cp(sm, w1np, 1024, tid);   // ow1^T (64 cols)
        __syncthreads();
        f32x4 acc[1] = {{0,0,0,0}};
        run_gemm<1>(sm, S_AS, lane, w * 16, acc);
        int n = w * 16 + m;
        float b1v = ob1[n], w2v = ow2[n];
        float part = 0.f;
        #pragma unroll
        for (int i = 0; i < 4; ++i) part += ssp(acc[0][i] + b1v) * w2v;
        #pragma unroll
        for (int mm = 1; mm < 64; mm <<= 1) part += __shfl_xor(part, mm, 64);
        float* fs = (float*)&sm[S_TS];
        if (lane == 0) fs[w] = part;
        __syncthreads();
        if (tid == 0) {
            float bsum = fs[0] + fs[1] + fs[2] + fs[3] + 16.0f * ob2[0];
            float add = 32.0f * bsum;
            if ((bid & 15) == 0) {
                float sb = 0.f;
                for (int j = 0; j < NB; ++j) sb += gbias[j];
                add += sb;
            }
            atomicAdd(&out[bid >> 4], add);
        }
    }
}

// ---------------------------------------------------------------------------
extern "C" void kernel_launch(void* const* d_in, const int* in_sizes, int n_in,
                              void* d_out, int out_size, void* d_ws, size_t ws_size,
                              hipStream_t stream) {
    SArgs a;
    a.pos  = (const float*)d_in[0];
    a.z    = (const int*)d_in[1];
    a.ei   = (const int*)d_in[3];
    a.dom  = (const int*)d_in[4];
    a.emb  = (const float*)d_in[5];
    a.mw1  = (const float*)d_in[6];
    a.mb1  = (const float*)d_in[7];
    a.mw2  = (const float*)d_in[8];
    a.mb2  = (const float*)d_in[9];
    a.cf1  = (const float*)d_in[10];
    a.cf2w = (const float*)d_in[11];
    const float* cf2b = (const float*)d_in[12];
    a.intw = (const float*)d_in[13];
    const float* intb = (const float*)d_in[14];
    a.ow1  = (const float*)d_in[15];
    const float* ob1  = (const float*)d_in[16];
    const float* ow2  = (const float*)d_in[17];
    const float* ob2  = (const float*)d_in[18];
    a.dome = (const float*)d_in[19];
    a.fw1  = (const float*)d_in[20];
    a.fb1  = (const float*)d_in[21];
    a.fw2  = (const float*)d_in[22];
    a.fb2  = (const float*)d_in[23];
    a.bw   = (const float*)d_in[26];
    a.bb   = (const float*)d_in[27];

    char* ws = (char*)d_ws;
    a.epack  = (uint2*)(ws + 0);               // 2 MB
    a.tab    = (uint*)(ws + 2*MB);             // 1.5 MB (6 x 1024 x 64)
    a.h      = (float*)(ws + 4*MB);            // 4 MB
    a.xA     = (uint*)(ws + 8*MB);             // 2 MB
    uint* xB = (uint*)(ws + 10*MB);            // 2 MB
    a.gbias  = (float*)(ws + 12*MB);           // 128 B
    a.wpack  = (uint*)(ws + 12*MB + 4096);     // 901 KB
    a.out = (float*)d_out;
    a.out_size = out_size;

    k_setup<<<512, 256, 0, stream>>>(a);

    const uint* xr = a.xA;
    uint* xw = xB;
    for (int l = 0; l < NLAYER; ++l) {
        const uint* w2p = a.wpack + (6 + l) * 8192;
        const uint* w3p = a.wpack + (12 + l) * 8192;
        if (l < NLAYER - 1) {
            k_layer<false><<<512, 256, 0, stream>>>(
                a.h, xr, xw, a.tab + l*GTAB*64, a.epack, w2p, w3p,
                a.wpack + (l + 1) * 8192, cf2b + l*128, intb + l*128,
                a.wpack, l + 1, a.mb1, a.mb2, a.tab + (l + 1)*GTAB*64,
                ob1, ow2, ob2, a.gbias, a.out);
        } else {
            k_layer<true><<<512, 256, 0, stream>>>(
                a.h, xr, xw, a.tab + l*GTAB*64, a.epack, w2p, w3p,
                a.wpack + OW1P_OFF, cf2b + l*128, intb + l*128,
                a.wpack, 0, a.mb1, a.mb2, a.tab,
                ob1, ow2, ob2, a.gbias, a.out);
        }
        const uint* tmp = xr; xr = xw; xw = (uint*)tmp;
    }
}

// Round 7
// 273.225 us; speedup vs baseline: 1.4164x; 1.4164x over previous
//
#include <hip/hip_runtime.h>
#include <math.h>

using uint = unsigned int;
typedef _Float16 h2    __attribute__((ext_vector_type(2)));
typedef _Float16 f16x8 __attribute__((ext_vector_type(8)));
typedef float    f32x4 __attribute__((ext_vector_type(4)));

#define N_ATOMS 8192
#define NEDGE   262144
#define KNBR    32
#define NGAUSS  50
#define NLAYER  6
#define NB      32
#define GTAB    1024
#define DMAX    8.6603f
#define FCUT    10.0f
#define MB      1048576

// MFMA LDS geometry (uints). Stride 76: 16B-aligned frags, 2-way banks (free).
#define LSTRIDE 76
#define S_WT    0               // 128*76 = 9728
#define S_AS    9728            // 16*76 = 1216
#define S_TS    10944           // 1216
#define GEMM_SMEM 12160         // 48.6 KB -> 3 blocks/CU

// table kernel LDS (uints)
#define T_W1    0               // 4096
#define T_W2    4096            // 8192
#define T_RBF   12288           // 1024
#define T_HID   13312           // 2048
#define TAB_SMEM 15360

// wpack layout (uints)
#define OW1P_OFF 147456         // 18 mats 128x128 (c,kp): cf1 x6 | cf2 x6 | int x6
#define M1_OFF   151552         // + ow1^T 64x64 (c,kp)
#define M2_OFF   176128         // + mlp_w1 f16 (kp,c) x6
#define WPACK_N  225280         // + mlp_w2 f16 (kp,c) x6

__device__ __forceinline__ float ssp(float x) {
    return fmaxf(x, 0.0f) + log1pf(expf(-fabsf(x))) - 0.69314718055994531f;
}
__device__ __forceinline__ uint pack2(float a, float b) {
    union { h2 h; uint u; } x;
    h2 v; v.x = (_Float16)a; v.y = (_Float16)b; x.h = v; return x.u;
}
__device__ __forceinline__ h2 u2h(uint u) {
    union { uint u; h2 h; } x; x.u = u; return x.h;
}
__device__ __forceinline__ uint h2u(h2 h) {
    union { h2 h; uint u; } x; x.h = h; return x.u;
}
__device__ __forceinline__ float fdot2f(h2 a, h2 b, float c) {
#if __has_builtin(__builtin_amdgcn_fdot2)
    return __builtin_amdgcn_fdot2(a, b, c, false);
#else
    return fmaf((float)a.y, (float)b.y, fmaf((float)a.x, (float)b.x, c));
#endif
}

// copy pre-packed W^T (c,kp) 64-stride -> LDS stride-76
__device__ __forceinline__ void stage_cp(uint* sm, const uint* __restrict__ src,
                                         int n16, int tid) {
    for (int i = tid; i < n16; i += 256) {
        uint4 v = ((const uint4*)src)[i];
        *(uint4*)&sm[(i >> 4) * LSTRIDE + (i & 15) * 4] = v;
    }
}

// MFMA: D[16 rows][NCT*16 cols] = As(16x128) @ WT^T, cols base nb
template<int NCT>
__device__ __forceinline__ void run_gemm(const uint* sm, int as_off, int lane,
                                         int nb, f32x4* acc) {
    int m = lane & 15, q = lane >> 4;
    #pragma unroll
    for (int ks = 0; ks < 4; ++ks) {
        f16x8 a = *(const f16x8*)&sm[as_off + m * LSTRIDE + q * 4 + ks * 16];
        #pragma unroll
        for (int ct = 0; ct < NCT; ++ct) {
            f16x8 b = *(const f16x8*)&sm[S_WT + (nb + ct * 16 + m) * LSTRIDE + q * 4 + ks * 16];
            acc[ct] = __builtin_amdgcn_mfma_f32_16x16x32_f16(a, b, acc[ct], 0, 0, 0);
        }
    }
}

struct SArgs {
    const float *pos; const int *z; const int *ei; const int *dom;
    const float *emb;
    const float *cf1; const float *cf2w; const float *intw; const float *ow1;
    const float *mw1; const float *mw2;
    const float *dome; const float *fw1; const float *fb1;
    const float *fw2; const float *fb2; const float *bw; const float *bb;
    uint2 *epack; float *h; uint *xA;
    float *gbias; uint *wpack; float *out; int out_size;
};

// ---------------------------------------------------------------------------
// setup: zero-out + wcvt + epack + embed + x0 GEMM + film (blocks 32..63)
__global__ void __launch_bounds__(256) k_setup(SArgs a) {
    __shared__ __align__(16) uint sm[S_AS + 1216];
    const int tid = threadIdx.x, bid = blockIdx.x;
    const int gidx = bid * 256 + tid, gsz = 512 * 256;
    const int lane = tid & 63, w = tid >> 6;
    const int m = lane & 15, q = lane >> 4;
    const int rowbase = bid * 16;

    for (int i = gidx; i < a.out_size; i += gsz) a.out[i] = 0.0f;

    // f16 weight pack
    for (int idx = gidx; idx < WPACK_N; idx += gsz) {
        if (idx < OW1P_OFF) {
            int mat = idx >> 13, e = idx & 8191;
            int kp = e >> 7, c = e & 127;
            const float* src = (mat < 6) ? (a.cf1 + mat * 16384)
                            : (mat < 12) ? (a.cf2w + (mat - 6) * 16384)
                                         : (a.intw + (mat - 12) * 16384);
            a.wpack[mat * 8192 + c * 64 + kp] =
                pack2(src[2 * kp * 128 + c], src[(2 * kp + 1) * 128 + c]);
        } else if (idx < M1_OFF) {
            int e = idx - OW1P_OFF;
            int kp = e >> 6, c = e & 63;
            a.wpack[OW1P_OFF + c * 64 + kp] =
                pack2(a.ow1[2 * kp * 64 + c], a.ow1[(2 * kp + 1) * 64 + c]);
        } else if (idx < M2_OFF) {
            int e = idx - M1_OFF;
            int l = e >> 12, r = e & 4095;
            int kp = r >> 7, c = r & 127;
            int g0 = 2 * kp;
            float va = (g0 < NGAUSS)     ? a.mw1[l*NGAUSS*128 + g0*128 + c]     : 0.f;
            float vb = (g0 + 1 < NGAUSS) ? a.mw1[l*NGAUSS*128 + (g0+1)*128 + c] : 0.f;
            a.wpack[idx] = pack2(va, vb);
        } else {
            int e = idx - M2_OFF;
            int l = e >> 13, r = e & 8191;
            int kp = r >> 7, c = r & 127;
            a.wpack[idx] = pack2(a.mw2[l*16384 + 2*kp*128 + c],
                                 a.mw2[l*16384 + (2*kp+1)*128 + c]);
        }
    }

    // epack: local 512 edges
    const float invdelta = (float)(GTAB - 1) / DMAX;
    #pragma unroll
    for (int t = 0; t < 2; ++t) {
        int e = rowbase * KNBR + t * 256 + tid;
        int s = a.ei[e], d = a.ei[NEDGE + e];
        float dx = a.pos[3*s] - a.pos[3*d];
        float dy = a.pos[3*s+1] - a.pos[3*d+1];
        float dz = a.pos[3*s+2] - a.pos[3*d+2];
        float dist = sqrtf(dx*dx + dy*dy + dz*dz);
        float u = dist * invdelta;
        int i0 = (int)u; i0 = (i0 < GTAB - 2) ? i0 : (GTAB - 2);
        float t2 = u - (float)i0;
        uint tb = pack2(t2, 0.0f) & 0xffffu;
        uint2 ep; ep.x = (uint)s; ep.y = (tb << 16) | (uint)i0;
        a.epack[e] = ep;
    }

    // embed -> h (f32) + As (f16)
    for (int i = tid; i < 1024; i += 256) {
        int r = i >> 6, f2 = i & 63;
        int zz = a.z[rowbase + r];
        float2 v = *(const float2*)&a.emb[zz * 128 + f2 * 2];
        *(float2*)&a.h[(rowbase + r) * 128 + f2 * 2] = v;
        sm[S_AS + r * LSTRIDE + f2] = pack2(v.x, v.y);
    }
    // WT <- cf1_0 (fp32 direct; wpack not yet visible within this kernel)
    for (int i = tid; i < 2048; i += 256) {
        int m4 = i >> 7, c = i & 127;
        float v[8];
        #pragma unroll
        for (int j = 0; j < 8; ++j) v[j] = a.cf1[(8 * m4 + j) * 128 + c];
        uint4 pk; pk.x = pack2(v[0], v[1]); pk.y = pack2(v[2], v[3]);
        pk.z = pack2(v[4], v[5]); pk.w = pack2(v[6], v[7]);
        *(uint4*)&sm[c * LSTRIDE + m4 * 4] = pk;
    }
    __syncthreads();
    {   // x0 = h @ W1_0 -> xA
        f32x4 acc[2] = {{0,0,0,0},{0,0,0,0}};
        run_gemm<2>(sm, S_AS, lane, w * 32, acc);
        #pragma unroll
        for (int ct = 0; ct < 2; ++ct) {
            int n = w * 32 + ct * 16 + m;
            #pragma unroll
            for (int i = 0; i < 4; ++i) {
                float v = acc[ct][i];
                float u = __shfl_xor(v, 1, 64);
                if (!(lane & 1))
                    a.xA[(rowbase + q * 4 + i) * 64 + (n >> 1)] = pack2(v, u);
            }
        }
    }
    __syncthreads();
    if (bid >= 32 && bid < 64) {
        // FiLM beta sum (gamma path multiplies zeros), graph = bid-32
        int g = bid - 32;
        float* fs = (float*)sm;   // des@0, a1@64, film@192, part@320
        if (tid < 64) fs[tid] = a.dome[a.dom[g] * 64 + tid];
        __syncthreads();
        if (tid < 128) {
            float acc = a.fb1[tid];
            for (int i = 0; i < 64; ++i) acc = fmaf(fs[i], a.fw1[i*128 + tid], acc);
            fs[64 + tid] = fmaxf(acc, 0.0f);
        }
        __syncthreads();
        if (tid < 128) {
            float acc = a.fb2[tid];
            for (int i = 0; i < 128; ++i) acc = fmaf(fs[64+i], a.fw2[i*128 + tid], acc);
            fs[192 + tid] = acc;
        }
        __syncthreads();
        if (tid < 128) {
            float acc = a.bb[tid];
            for (int i = 0; i < 128; ++i) acc = fmaf(fs[192+i], a.bw[i*128 + tid], acc);
            #pragma unroll
            for (int off = 32; off > 0; off >>= 1) acc += __shfl_down(acc, off, 64);
            if ((tid & 63) == 0) fs[320 + (tid >> 6)] = acc;
        }
        __syncthreads();
        if (tid == 0) a.gbias[g] = fs[320] + fs[321];
    }
}

// ---------------------------------------------------------------------------
// filter tables from f16 wpack: 192 blocks = 6 layers x 32 chunks x 32 rows
__global__ void __launch_bounds__(256) k_table(
    const uint* __restrict__ wpack, const float* __restrict__ mb1,
    const float* __restrict__ mb2, uint* __restrict__ tab) {
    __shared__ __align__(16) uint sm[TAB_SMEM];
    const int tid = threadIdx.x;
    const int l = blockIdx.x >> 5;
    const int base = (blockIdx.x & 31) * 32;
    { const uint4* s4 = (const uint4*)(wpack + M1_OFF + l*4096);
      uint4* d4 = (uint4*)&sm[T_W1];
      for (int i = tid; i < 1024; i += 256) d4[i] = s4[i]; }
    { const uint4* s4 = (const uint4*)(wpack + M2_OFF + l*8192);
      uint4* d4 = (uint4*)&sm[T_W2];
      for (int i = tid; i < 2048; i += 256) d4[i] = s4[i]; }
    const float delta = DMAX / (float)(GTAB - 1);
    const float gstep = FCUT / (float)(NGAUSS - 1);
    const float coeff = -0.5f / (gstep * gstep);
    for (int i = tid; i < 1024; i += 256) {
        int r = i >> 5, kp = i & 31;
        float dv = (float)(base + r) * delta;
        int g0 = 2 * kp;
        float v0 = 0.f, v1 = 0.f;
        if (g0 < NGAUSS)     { float t = dv - (float)g0 * gstep;     v0 = expf(coeff*t*t); }
        if (g0 + 1 < NGAUSS) { float t = dv - (float)(g0+1) * gstep; v1 = expf(coeff*t*t); }
        sm[T_RBF + i] = pack2(v0, v1);
    }
    __syncthreads();
    int tx = tid & 31, ty = tid >> 5, c0 = tx * 4, tr0 = ty * 4;
    float acc[4][4];
    #pragma unroll
    for (int i = 0; i < 4; ++i) { acc[i][0]=0.f; acc[i][1]=0.f; acc[i][2]=0.f; acc[i][3]=0.f; }
    #pragma unroll
    for (int oct = 0; oct < 8; ++oct) {              // stage 1: K=50 (32 pairs)
        int kp0 = oct * 4;
        uint4 w_[4];
        #pragma unroll
        for (int p = 0; p < 4; ++p) w_[p] = *(const uint4*)&sm[T_W1 + (kp0+p)*128 + c0];
        #pragma unroll
        for (int i = 0; i < 4; ++i) {
            uint4 av = *(const uint4*)&sm[T_RBF + (tr0+i)*32 + kp0];
            uint aa[4] = {av.x, av.y, av.z, av.w};
            #pragma unroll
            for (int p = 0; p < 4; ++p) {
                h2 ap = u2h(aa[p]);
                acc[i][0] = fdot2f(ap, u2h(w_[p].x), acc[i][0]);
                acc[i][1] = fdot2f(ap, u2h(w_[p].y), acc[i][1]);
                acc[i][2] = fdot2f(ap, u2h(w_[p].z), acc[i][2]);
                acc[i][3] = fdot2f(ap, u2h(w_[p].w), acc[i][3]);
            }
        }
    }
    float4 b1v = *(const float4*)&mb1[l*128 + c0];
    #pragma unroll
    for (int i = 0; i < 4; ++i) {
        uint2 o;
        o.x = pack2(ssp(acc[i][0] + b1v.x), ssp(acc[i][1] + b1v.y));
        o.y = pack2(ssp(acc[i][2] + b1v.z), ssp(acc[i][3] + b1v.w));
        *(uint2*)&sm[T_HID + (tr0+i)*64 + (c0 >> 1)] = o;
    }
    __syncthreads();
    float acc2[4][4];
    #pragma unroll
    for (int i = 0; i < 4; ++i) { acc2[i][0]=0.f; acc2[i][1]=0.f; acc2[i][2]=0.f; acc2[i][3]=0.f; }
    #pragma unroll 4
    for (int oct = 0; oct < 16; ++oct) {             // stage 2: K=128
        int kp0 = oct * 4;
        uint4 w_[4];
        #pragma unroll
        for (int p = 0; p < 4; ++p) w_[p] = *(const uint4*)&sm[T_W2 + (kp0+p)*128 + c0];
        #pragma unroll
        for (int i = 0; i < 4; ++i) {
            uint4 av = *(const uint4*)&sm[T_HID + (tr0+i)*64 + kp0];
            uint aa[4] = {av.x, av.y, av.z, av.w};
            #pragma unroll
            for (int p = 0; p < 4; ++p) {
                h2 ap = u2h(aa[p]);
                acc2[i][0] = fdot2f(ap, u2h(w_[p].x), acc2[i][0]);
                acc2[i][1] = fdot2f(ap, u2h(w_[p].y), acc2[i][1]);
                acc2[i][2] = fdot2f(ap, u2h(w_[p].z), acc2[i][2]);
                acc2[i][3] = fdot2f(ap, u2h(w_[p].w), acc2[i][3]);
            }
        }
    }
    float4 b2v = *(const float4*)&mb2[l*128 + c0];
    #pragma unroll
    for (int i = 0; i < 4; ++i) {
        int row = base + tr0 + i;
        float dv = (float)row * delta;
        float Cd = 0.5f * (cosf(dv * 0.3141592653589793f) + 1.0f);
        uint2 o;
        o.x = pack2((acc2[i][0] + b2v.x)*Cd, (acc2[i][1] + b2v.y)*Cd);
        o.y = pack2((acc2[i][2] + b2v.z)*Cd, (acc2[i][3] + b2v.w)*Cd);
        *(uint2*)&tab[(l*GTAB + row)*64 + (c0 >> 1)] = o;
    }
}

// ---------------------------------------------------------------------------
// edge gather, LDS-free, 1 wave per atom (lanes = 64 feature-pairs), pk-f16.
// epack preloaded by lanes 0..31 and broadcast via readlane.
__global__ void __launch_bounds__(256) k_gather(
    const uint* __restrict__ xin, const uint* __restrict__ tabl,
    const uint2* __restrict__ epack, uint* __restrict__ agg) {
    const int tid = threadIdx.x;
    const int lane = tid & 63;
    const int atom = blockIdx.x * 4 + (tid >> 6);
    const int ebase = atom * KNBR;
    uint2 ep = epack[ebase + (lane & 31)];
    uint sv = ep.x, yv = ep.y;
    h2 acc; acc.x = (_Float16)0; acc.y = (_Float16)0;
    #pragma unroll 8
    for (int k = 0; k < KNBR; ++k) {
        uint s = __shfl(sv, k, 64);
        uint y = __shfl(yv, k, 64);
        int i0 = (int)(y & 0xffffu);
        uint th = y >> 16;
        h2 t2 = u2h(th | (th << 16));
        h2 f0 = u2h(tabl[i0 * 64 + lane]);
        h2 f1 = u2h(tabl[(i0 + 1) * 64 + lane]);
        h2 xs = u2h(xin[s * 64 + lane]);
        h2 wv = f0 + t2 * (f1 - f0);
        acc = acc + xs * wv;
    }
    agg[atom * 64 + lane] = h2u(acc);
}

// ---------------------------------------------------------------------------
// GEMM part of a layer: Ts=ssp(agg@W2+b2); h+=Ts@W3+b3; x_next=h@W1n (or readout)
template<bool LAST>
__global__ void __launch_bounds__(256) k_gemmL(
    float* __restrict__ h, const uint* __restrict__ agg, uint* __restrict__ xout,
    const uint* __restrict__ w2p, const uint* __restrict__ w3p,
    const uint* __restrict__ w1np,
    const float* __restrict__ b2, const float* __restrict__ b3,
    const float* __restrict__ ob1, const float* __restrict__ ow2,
    const float* __restrict__ ob2, const float* __restrict__ gbias,
    float* __restrict__ out) {
    __shared__ __align__(16) uint sm[GEMM_SMEM];
    const int tid = threadIdx.x, bid = blockIdx.x;
    const int lane = tid & 63, w = tid >> 6;
    const int m = lane & 15, q = lane >> 4;
    const int rowbase = bid * 16;

    stage_cp(sm, w2p, 2048, tid);
    {   // AS <- agg rows (uint4 coalesced)
        const uint4* a4 = (const uint4*)(agg + rowbase * 64);
        for (int i = tid; i < 256; i += 256) {
            uint4 v = a4[i];
            *(uint4*)&sm[S_AS + (i >> 4) * LSTRIDE + (i & 15) * 4] = v;
        }
    }
    __syncthreads();
    {   // Ts = ssp(As @ W2 + b2)
        f32x4 acc[2] = {{0,0,0,0},{0,0,0,0}};
        run_gemm<2>(sm, S_AS, lane, w * 32, acc);
        #pragma unroll
        for (int ct = 0; ct < 2; ++ct) {
            int n = w * 32 + ct * 16 + m;
            float bv = b2[n];
            #pragma unroll
            for (int i = 0; i < 4; ++i) {
                float v = ssp(acc[ct][i] + bv);
                float u = __shfl_xor(v, 1, 64);
                if (!(lane & 1))
                    sm[S_TS + (q * 4 + i) * LSTRIDE + (n >> 1)] = pack2(v, u);
            }
        }
    }
    __syncthreads();
    stage_cp(sm, w3p, 2048, tid);
    __syncthreads();
    {   // h += Ts @ W3 + b3 ; As <- h_new
        f32x4 acc[2] = {{0,0,0,0},{0,0,0,0}};
        run_gemm<2>(sm, S_TS, lane, w * 32, acc);
        #pragma unroll
        for (int ct = 0; ct < 2; ++ct) {
            int n = w * 32 + ct * 16 + m;
            float bv = b3[n];
            #pragma unroll
            for (int i = 0; i < 4; ++i) {
                int r = rowbase + q * 4 + i;
                float hv = h[r * 128 + n] + acc[ct][i] + bv;
                h[r * 128 + n] = hv;
                float u = __shfl_xor(hv, 1, 64);
                if (!(lane & 1))
                    sm[S_AS + (q * 4 + i) * LSTRIDE + (n >> 1)] = pack2(hv, u);
            }
        }
    }
    __syncthreads();
    if (!LAST) {
        stage_cp(sm, w1np, 2048, tid);
        __syncthreads();
        f32x4 acc[2] = {{0,0,0,0},{0,0,0,0}};
        run_gemm<2>(sm, S_AS, lane, w * 32, acc);
        #pragma unroll
        for (int ct = 0; ct < 2; ++ct) {
            int n = w * 32 + ct * 16 + m;
            #pragma unroll
            for (int i = 0; i < 4; ++i) {
                float v = acc[ct][i];
                float u = __shfl_xor(v, 1, 64);
                if (!(lane & 1))
                    xout[(rowbase + q * 4 + i) * 64 + (n >> 1)] = pack2(v, u);
            }
        }
    } else {
        stage_cp(sm, w1np, 1024, tid);   // ow1^T (64 cols)
        __syncthreads();
        f32x4 acc[1] = {{0,0,0,0}};
        run_gemm<1>(sm, S_AS, lane, w * 16, acc);
        int n = w * 16 + m;
        float b1v = ob1[n], w2v = ow2[n];
        float part = 0.f;
        #pragma unroll
        for (int i = 0; i < 4; ++i) part += ssp(acc[0][i] + b1v) * w2v;
        #pragma unroll
        for (int mm = 1; mm < 64; mm <<= 1) part += __shfl_xor(part, mm, 64);
        float* fs = (float*)&sm[S_TS];
        if (lane == 0) fs[w] = part;
        __syncthreads();
        if (tid == 0) {
            float bsum = fs[0] + fs[1] + fs[2] + fs[3] + 16.0f * ob2[0];
            float add = 32.0f * bsum;
            if ((bid & 15) == 0) {
                float sb = 0.f;
                for (int j = 0; j < NB; ++j) sb += gbias[j];
                add += sb;
            }
            atomicAdd(&out[bid >> 4], add);
        }
    }
}

// ---------------------------------------------------------------------------
extern "C" void kernel_launch(void* const* d_in, const int* in_sizes, int n_in,
                              void* d_out, int out_size, void* d_ws, size_t ws_size,
                              hipStream_t stream) {
    SArgs a;
    a.pos  = (const float*)d_in[0];
    a.z    = (const int*)d_in[1];
    a.ei   = (const int*)d_in[3];
    a.dom  = (const int*)d_in[4];
    a.emb  = (const float*)d_in[5];
    a.mw1  = (const float*)d_in[6];
    const float* mb1 = (const float*)d_in[7];
    a.mw2  = (const float*)d_in[8];
    const float* mb2 = (const float*)d_in[9];
    a.cf1  = (const float*)d_in[10];
    a.cf2w = (const float*)d_in[11];
    const float* cf2b = (const float*)d_in[12];
    a.intw = (const float*)d_in[13];
    const float* intb = (const float*)d_in[14];
    a.ow1  = (const float*)d_in[15];
    const float* ob1  = (const float*)d_in[16];
    const float* ow2  = (const float*)d_in[17];
    const float* ob2  = (const float*)d_in[18];
    a.dome = (const float*)d_in[19];
    a.fw1  = (const float*)d_in[20];
    a.fb1  = (const float*)d_in[21];
    a.fw2  = (const float*)d_in[22];
    a.fb2  = (const float*)d_in[23];
    a.bw   = (const float*)d_in[26];
    a.bb   = (const float*)d_in[27];

    char* ws = (char*)d_ws;
    a.epack   = (uint2*)(ws + 0);               // 2 MB
    uint* tab = (uint*)(ws + 2*MB);             // 1.5 MB
    a.h       = (float*)(ws + 4*MB);            // 4 MB
    a.xA      = (uint*)(ws + 8*MB);             // 2 MB
    uint* xB  = (uint*)(ws + 10*MB);            // 2 MB
    uint* agg = (uint*)(ws + 12*MB);            // 2 MB
    a.gbias   = (float*)(ws + 14*MB);           // 128 B
    a.wpack   = (uint*)(ws + 14*MB + 4096);     // 901 KB
    a.out = (float*)d_out;
    a.out_size = out_size;

    k_setup<<<512, 256, 0, stream>>>(a);
    k_table<<<192, 256, 0, stream>>>(a.wpack, mb1, mb2, tab);

    const uint* xr = a.xA;
    uint* xw = xB;
    for (int l = 0; l < NLAYER; ++l) {
        k_gather<<<N_ATOMS/4, 256, 0, stream>>>(xr, tab + l*GTAB*64, a.epack, agg);
        const uint* w2p = a.wpack + (6 + l) * 8192;
        const uint* w3p = a.wpack + (12 + l) * 8192;
        if (l < NLAYER - 1) {
            k_gemmL<false><<<512, 256, 0, stream>>>(
                a.h, agg, xw, w2p, w3p, a.wpack + (l + 1) * 8192,
                cf2b + l*128, intb + l*128, ob1, ow2, ob2, a.gbias, a.out);
        } else {
            k_gemmL<true><<<512, 256, 0, stream>>>(
                a.h, agg, xw, w2p, w3p, a.wpack + OW1P_OFF,
                cf2b + l*128, intb + l*128, ob1, ow2, ob2, a.gbias, a.out);
        }
        const uint* tmp = xr; xr = xw; xw = (uint*)tmp;
    }
}